// Round 6
// baseline (17539.113 us; speedup 1.0000x reference)
//
#include <hip/hip_runtime.h>
#include <hip/hip_bf16.h>
#include <stdint.h>

#define BB   8
#define CCH  128
#define HH   256
#define WWD  256
#define OCC  64
#define HWW  (HH*WWD)
#define PLANE (BB*HWW*32)          // elems per 32-ch plane of xn2
#define NSLOT 2448                 // 18 rows x 4 granules x 34 px (16B slots)

typedef __attribute__((ext_vector_type(8)))  short  bf16x8;
typedef __attribute__((ext_vector_type(16))) float  f32x16;
typedef __attribute__((ext_vector_type(4)))  unsigned int u32x4;
typedef __attribute__((ext_vector_type(2)))  float  f32x2;

static __device__ __forceinline__ unsigned cvt_pk_bf16(float lo, float hi) {
    unsigned r;
    asm("v_cvt_pk_bf16_f32 %0, %1, %2" : "=v"(r) : "v"(lo), "v"(hi));
    return r;
}
static __device__ __forceinline__ float bf16lo_to_f(unsigned u) {
    union { unsigned u; float f; } c; c.u = u << 16; return c.f;
}
static __device__ __forceinline__ float bf16hi_to_f(unsigned u) {
    union { unsigned u; float f; } c; c.u = u & 0xffff0000u; return c.f;
}

// square / cube of a packed bf16x8 fragment (f32 math, one bf16 round)
static __device__ __forceinline__ bf16x8 frag_sq(bf16x8 a) {
    u32x4 u = __builtin_bit_cast(u32x4, a), o;
    #pragma unroll
    for (int k = 0; k < 4; ++k) {
        float f0 = bf16lo_to_f(u[k]), f1 = bf16hi_to_f(u[k]);
        o[k] = cvt_pk_bf16(f0 * f0, f1 * f1);
    }
    return __builtin_bit_cast(bf16x8, o);
}
static __device__ __forceinline__ bf16x8 frag_cube(bf16x8 a) {
    u32x4 u = __builtin_bit_cast(u32x4, a), o;
    #pragma unroll
    for (int k = 0; k < 4; ++k) {
        float f0 = bf16lo_to_f(u[k]), f1 = bf16hi_to_f(u[k]);
        o[k] = cvt_pk_bf16(f0 * f0 * f0, f1 * f1 * f1);
    }
    return __builtin_bit_cast(bf16x8, o);
}

// Repack Wc (OC, Q*C, 3, 3) fp32 -> Wb3 in 32x32x16-fragment lane order.
// frag f = ((tq*4 + cc)*4) + kh*2 + nt, tq = tap*3 + q.
// lane -> oc = nt*32 + (lane&31), k = cc*32 + kh*16 + (lane>>5)*8 + j (j=0..7).
__global__ void prep_w(const float* __restrict__ Wc, unsigned short* __restrict__ Wb3) {
    int t = blockIdx.x * 256 + threadIdx.x;       // 27648 tasks, one bf16x8 each
    int lane = t & 63;
    int f    = t >> 6;                            // 0..431
    int nt   = f & 1;
    int kh   = (f >> 1) & 1;
    int cc   = (f >> 2) & 3;
    int tq   = f >> 4;                            // 0..26
    int q    = tq % 3;
    int tap  = tq / 3;
    int oc   = nt * 32 + (lane & 31);
    int kb   = cc * 32 + kh * 16 + (lane >> 5) * 8;
    u32x4 o;
    #pragma unroll
    for (int k = 0; k < 4; ++k) {
        float v0 = Wc[(size_t)(oc * 384 + q * 128 + kb + 2 * k) * 9 + tap];
        float v1 = Wc[(size_t)(oc * 384 + q * 128 + kb + 2 * k + 1) * 9 + tap];
        o[k] = cvt_pk_bf16(v0, v1);
    }
    *(u32x4*)(Wb3 + (size_t)t * 8) = o;
}

// Per-pixel LayerNorm over C=128; write xn2 as 4 planes [cc][b][y][x][32ch] bf16
__global__ __launch_bounds__(256) void ln_kernel(
        const float* __restrict__ x, const float* __restrict__ gamma,
        const float* __restrict__ beta, unsigned short* __restrict__ xn2) {
    int p  = blockIdx.x * 256 + threadIdx.x;      // global pixel
    int b  = p >> 16;
    int hw = p & 65535;
    const float* xb = x + (size_t)b * CCH * HWW + hw;
    unsigned buf[64];
    float sum = 0.f, sumsq = 0.f;
    #pragma unroll
    for (int cp = 0; cp < 64; ++cp) {
        float v0 = xb[(size_t)(2 * cp) * HWW];
        float v1 = xb[(size_t)(2 * cp + 1) * HWW];
        sum   += v0 + v1;
        sumsq += v0 * v0 + v1 * v1;
        buf[cp] = cvt_pk_bf16(v0, v1);
    }
    float mu  = sum * (1.f / 128.f);
    float var = sumsq * (1.f / 128.f) - mu * mu;
    float rs  = rsqrtf(var + 1e-5f);
    size_t pix = (size_t)p * 32;
    #pragma unroll
    for (int g = 0; g < 16; ++g) {
        u32x4 o;
        #pragma unroll
        for (int k = 0; k < 4; ++k) {
            int cp = g * 4 + k;
            float f0 = bf16lo_to_f(buf[cp]);
            float f1 = bf16hi_to_f(buf[cp]);
            int c0 = cp * 2, c1 = cp * 2 + 1;
            float y0 = fmaf((f0 - mu) * rs, gamma[c0], beta[c0]);
            float y1 = fmaf((f1 - mu) * rs, gamma[c1], beta[c1]);
            o[k] = cvt_pk_bf16(y0, y1);
        }
        *(u32x4*)(xn2 + (size_t)(g >> 2) * PLANE + pix + (g & 3) * 8) = o;
    }
}

// Implicit-GEMM conv, 32x32x16 MFMA. Block = 16 rows x 32 px x 64 oc; 4 waves,
// wave = 4 rows (M=128) x 64 oc. LDS holds xn only (powers computed in-register
// at A-load). Double-buffered LDS: chunk cc+1 staged (drip-fed reg loads during
// taps 0..9, ds_write after tap 26) while cc's 27 taps run.
__global__ __launch_bounds__(256, 2) void conv_kernel(
        const unsigned short* __restrict__ xn2,
        const unsigned short* __restrict__ Wb3,
        float* __restrict__ out) {
    // L[buf][slot = (row*4 + granule)*34 + px][16B] : 2 x 39168 B
    __shared__ __align__(16) unsigned char L[2][NSLOT * 16];

    int bid = blockIdx.x;
    int bx  = bid & 7;           // x tile (8)
    int by  = (bid >> 3) & 15;   // y tile (16)
    int b   = bid >> 7;          // batch (8)
    int x0  = bx * 32;
    int y0  = by * 16;
    int tid  = threadIdx.x;
    int lane = tid & 63;
    int w    = tid >> 6;         // wave owns rows {4w..4w+3}
    int l31  = lane & 31;
    int kb   = lane >> 5;        // k-granule bit

    f32x16 acc[4][2];
    #pragma unroll
    for (int mt = 0; mt < 4; ++mt)
        #pragma unroll
        for (int nt = 0; nt < 2; ++nt)
            #pragma unroll
            for (int r = 0; r < 16; ++r)
                acc[mt][nt][r] = 0.f;

    // ---- staging geometry (cc-invariant): slot = it*256 + tid ----
    int offg[10];
    bool vld[10], wrk[10];
    #pragma unroll
    for (int it = 0; it < 10; ++it) {
        int slot = tid + it * 256;
        bool ok  = slot < NSLOT;
        int ii   = ok ? slot : 0;
        int row  = ii / 136;             // 136 = 4*34
        int rem  = ii - row * 136;
        int g2   = rem / 34;
        int px   = rem - g2 * 34;
        int yy   = y0 - 1 + row;
        int xx   = x0 - 1 + px;
        bool inb = ok && (unsigned)yy < 256u && (unsigned)xx < 256u;
        offg[it] = (yy * 256 + xx) * 32 + g2 * 8;
        vld[it]  = inb;
        wrk[it]  = ok;
    }

    const unsigned short* xpb = xn2 + (size_t)b * HWW * 32;
    const bf16x8* wlane = (const bf16x8*)Wb3 + lane;

    // ---- prologue: bulk-stage chunk 0 into L[0] ----
    u32x4 rs[10];
    #pragma unroll
    for (int it = 0; it < 10; ++it) {
        u32x4 v = (u32x4){0u, 0u, 0u, 0u};
        if (vld[it]) v = *(const u32x4*)(xpb + offg[it]);
        rs[it] = v;
    }
    #pragma unroll
    for (int it = 0; it < 10; ++it)
        if (wrk[it]) *(u32x4*)(&L[0][(tid + it * 256) * 16]) = rs[it];

    #pragma unroll 1
    for (int cc = 0; cc < 4; ++cc) {
        __syncthreads();               // staged buf ready; prev readers done
        const unsigned char* Pb = &L[cc & 1][0];
        const unsigned char* pa = Pb + (kb * 34 + l31) * 16;  // lane part of A addr
        const unsigned short* xpn = xpb + (size_t)(cc + 1) * PLANE;
        const bf16x8* wcc = wlane + (size_t)cc * 4 * 64;

        bf16x8 bv[2][2][2];            // [buf][nt][kh]
        #pragma unroll
        for (int nt = 0; nt < 2; ++nt)
            #pragma unroll
            for (int kh = 0; kh < 2; ++kh)
                bv[0][nt][kh] = wcc[(kh * 2 + nt) * 64];

        bf16x8 av1[4][2], avp[4][2];

        #pragma unroll
        for (int tq = 0; tq < 27; ++tq) {
            const int cur = tq & 1, nxt = cur ^ 1;
            const int q  = tq % 3;
            const int sp = tq / 3;
            const int ky = sp / 3, kx = sp % 3;

            // B prefetch for next tap
            if (tq < 26) {
                #pragma unroll
                for (int nt = 0; nt < 2; ++nt)
                    #pragma unroll
                    for (int kh = 0; kh < 2; ++kh)
                        bv[nxt][nt][kh] = wcc[((tq + 1) * 16 + kh * 2 + nt) * 64];
            }
            // drip-fed staging load for chunk cc+1 (after B prefetch: no
            // vmcnt entanglement forcing early drain)
            if (tq < 10 && cc < 3) {
                u32x4 v = (u32x4){0u, 0u, 0u, 0u};
                if (vld[tq]) v = *(const u32x4*)(xpn + offg[tq]);
                rs[tq] = v;
            }

            // A fragments for this q
            if (q == 0) {
                #pragma unroll
                for (int mt = 0; mt < 4; ++mt)
                    #pragma unroll
                    for (int kh = 0; kh < 2; ++kh)
                        av1[mt][kh] = *(const bf16x8*)(pa
                            + (((4 * w + mt + ky) * 4 + kh * 2) * 34 + kx) * 16);
            } else if (q == 1) {
                #pragma unroll
                for (int mt = 0; mt < 4; ++mt)
                    #pragma unroll
                    for (int kh = 0; kh < 2; ++kh)
                        avp[mt][kh] = frag_sq(av1[mt][kh]);
            } else {
                #pragma unroll
                for (int mt = 0; mt < 4; ++mt)
                    #pragma unroll
                    for (int kh = 0; kh < 2; ++kh)
                        avp[mt][kh] = frag_cube(av1[mt][kh]);
            }

            __builtin_amdgcn_s_setprio(1);
            #pragma unroll
            for (int kh = 0; kh < 2; ++kh)
                #pragma unroll
                for (int nt = 0; nt < 2; ++nt)
                    #pragma unroll
                    for (int mt = 0; mt < 4; ++mt)
                        acc[mt][nt] = __builtin_amdgcn_mfma_f32_32x32x16_bf16(
                            (q == 0) ? av1[mt][kh] : avp[mt][kh],
                            bv[cur][nt][kh], acc[mt][nt], 0, 0, 0);
            __builtin_amdgcn_s_setprio(0);
        }

        // write staged chunk cc+1 into the back buffer
        if (cc < 3) {
            unsigned char* Pn = &L[(cc & 1) ^ 1][0];
            #pragma unroll
            for (int it = 0; it < 10; ++it)
                if (wrk[it]) *(u32x4*)(Pn + (tid + it * 256) * 16) = rs[it];
        }
    }

    // ---- epilogue: fused PixelUnshuffle(2) ----
    // C/D 32x32: col(oc) = lane&31, row(px) = (reg&3) + 8*(reg>>2) + 4*(lane>>5)
    #pragma unroll
    for (int mt = 0; mt < 4; ++mt) {
        int y  = y0 + 4 * w + mt;
        int s  = mt & 1;                 // y&1 (y0, 4w even)
        int y2 = y >> 1;
        #pragma unroll
        for (int nt = 0; nt < 2; ++nt) {
            int oc = nt * 32 + l31;
            #pragma unroll
            for (int p = 0; p < 8; ++p) {
                const int r  = (p & 1) + (p >> 1) * 4;       // 0,1,4,5,8,9,12,13
                int px = (r & 3) + 8 * (r >> 2) + 4 * kb;
                int x  = x0 + px;
                int ch = oc * 4 + s * 2 + (x & 1);
                int x2 = x >> 1;
                size_t off = ((size_t)(b * 256 + ch) * 128 + y2) * 128 + x2;
                f32x2 v;
                v.x = acc[mt][nt][r];
                v.y = acc[mt][nt][r + 2];
                *(f32x2*)(out + off) = v;
            }
        }
    }
}

extern "C" void kernel_launch(void* const* d_in, const int* in_sizes, int n_in,
                              void* d_out, int out_size, void* d_ws, size_t ws_size,
                              hipStream_t stream) {
    const float* x     = (const float*)d_in[0];
    const float* gamma = (const float*)d_in[1];
    const float* beta  = (const float*)d_in[2];
    const float* Wc    = (const float*)d_in[3];
    float* out = (float*)d_out;

    const size_t xn_bytes = (size_t)4 * PLANE * 2;               // 134217728
    const size_t wb_bytes = (size_t)27648 * 16;                  // 442368
    if (ws_size < xn_bytes + wb_bytes) return;                   // visible failure
    unsigned short* xn2 = (unsigned short*)d_ws;
    unsigned short* Wb3 = (unsigned short*)((char*)d_ws + xn_bytes);

    hipLaunchKernelGGL(prep_w, dim3(108), dim3(256), 0, stream, Wc, Wb3);
    hipLaunchKernelGGL(ln_kernel, dim3(2048), dim3(256), 0, stream, x, gamma, beta, xn2);
    hipLaunchKernelGGL(conv_kernel, dim3(1024), dim3(256), 0, stream, xn2, Wb3, out);
}

// Round 7
// 9146.777 us; speedup vs baseline: 1.9175x; 1.9175x over previous
//
#include <hip/hip_runtime.h>
#include <hip/hip_bf16.h>
#include <stdint.h>

#define BB   8
#define CCH  128
#define HH   256
#define WWD  256
#define OCC  64
#define HWW  (HH*WWD)
#define PLANE (BB*HWW*32)          // elems per 32-ch plane of xn2
#define NSLOT 1360                 // 10 rows x 4 granules x 34 px (16B slots)

typedef __attribute__((ext_vector_type(8)))  short  bf16x8;
typedef __attribute__((ext_vector_type(16))) float  f32x16;
typedef __attribute__((ext_vector_type(4)))  unsigned int u32x4;
typedef __attribute__((ext_vector_type(2)))  float  f32x2;

static __device__ __forceinline__ unsigned cvt_pk_bf16(float lo, float hi) {
    unsigned r;
    asm("v_cvt_pk_bf16_f32 %0, %1, %2" : "=v"(r) : "v"(lo), "v"(hi));
    return r;
}
static __device__ __forceinline__ float bf16lo_to_f(unsigned u) {
    union { unsigned u; float f; } c; c.u = u << 16; return c.f;
}
static __device__ __forceinline__ float bf16hi_to_f(unsigned u) {
    union { unsigned u; float f; } c; c.u = u & 0xffff0000u; return c.f;
}

// square / cube of a packed bf16x8 fragment (f32 math, one bf16 round)
static __device__ __forceinline__ bf16x8 frag_sq(bf16x8 a) {
    u32x4 u = __builtin_bit_cast(u32x4, a), o;
    #pragma unroll
    for (int k = 0; k < 4; ++k) {
        float f0 = bf16lo_to_f(u[k]), f1 = bf16hi_to_f(u[k]);
        o[k] = cvt_pk_bf16(f0 * f0, f1 * f1);
    }
    return __builtin_bit_cast(bf16x8, o);
}
static __device__ __forceinline__ bf16x8 frag_cube(bf16x8 a) {
    u32x4 u = __builtin_bit_cast(u32x4, a), o;
    #pragma unroll
    for (int k = 0; k < 4; ++k) {
        float f0 = bf16lo_to_f(u[k]), f1 = bf16hi_to_f(u[k]);
        o[k] = cvt_pk_bf16(f0 * f0 * f0, f1 * f1 * f1);
    }
    return __builtin_bit_cast(bf16x8, o);
}

// Repack Wc (OC, Q*C, 3, 3) fp32 -> Wb3 in 32x32x16-fragment lane order.
// frag f = ((tq*4 + cc)*4) + kh*2 + nt, tq = tap*3 + q.
// lane -> oc = nt*32 + (lane&31), k = cc*32 + kh*16 + (lane>>5)*8 + j (j=0..7).
__global__ void prep_w(const float* __restrict__ Wc, unsigned short* __restrict__ Wb3) {
    int t = blockIdx.x * 256 + threadIdx.x;       // 27648 tasks, one bf16x8 each
    int lane = t & 63;
    int f    = t >> 6;                            // 0..431
    int nt   = f & 1;
    int kh   = (f >> 1) & 1;
    int cc   = (f >> 2) & 3;
    int tq   = f >> 4;                            // 0..26
    int q    = tq % 3;
    int tap  = tq / 3;
    int oc   = nt * 32 + (lane & 31);
    int kb   = cc * 32 + kh * 16 + (lane >> 5) * 8;
    u32x4 o;
    #pragma unroll
    for (int k = 0; k < 4; ++k) {
        float v0 = Wc[(size_t)(oc * 384 + q * 128 + kb + 2 * k) * 9 + tap];
        float v1 = Wc[(size_t)(oc * 384 + q * 128 + kb + 2 * k + 1) * 9 + tap];
        o[k] = cvt_pk_bf16(v0, v1);
    }
    *(u32x4*)(Wb3 + (size_t)t * 8) = o;
}

// Per-pixel LayerNorm over C=128; write xn2 as 4 planes [cc][b][y][x][32ch] bf16
__global__ __launch_bounds__(256) void ln_kernel(
        const float* __restrict__ x, const float* __restrict__ gamma,
        const float* __restrict__ beta, unsigned short* __restrict__ xn2) {
    int p  = blockIdx.x * 256 + threadIdx.x;      // global pixel
    int b  = p >> 16;
    int hw = p & 65535;
    const float* xb = x + (size_t)b * CCH * HWW + hw;
    unsigned buf[64];
    float sum = 0.f, sumsq = 0.f;
    #pragma unroll
    for (int cp = 0; cp < 64; ++cp) {
        float v0 = xb[(size_t)(2 * cp) * HWW];
        float v1 = xb[(size_t)(2 * cp + 1) * HWW];
        sum   += v0 + v1;
        sumsq += v0 * v0 + v1 * v1;
        buf[cp] = cvt_pk_bf16(v0, v1);
    }
    float mu  = sum * (1.f / 128.f);
    float var = sumsq * (1.f / 128.f) - mu * mu;
    float rs  = rsqrtf(var + 1e-5f);
    size_t pix = (size_t)p * 32;
    #pragma unroll
    for (int g = 0; g < 16; ++g) {
        u32x4 o;
        #pragma unroll
        for (int k = 0; k < 4; ++k) {
            int cp = g * 4 + k;
            float f0 = bf16lo_to_f(buf[cp]);
            float f1 = bf16hi_to_f(buf[cp]);
            int c0 = cp * 2, c1 = cp * 2 + 1;
            float y0 = fmaf((f0 - mu) * rs, gamma[c0], beta[c0]);
            float y1 = fmaf((f1 - mu) * rs, gamma[c1], beta[c1]);
            o[k] = cvt_pk_bf16(y0, y1);
        }
        *(u32x4*)(xn2 + (size_t)(g >> 2) * PLANE + pix + (g & 3) * 8) = o;
    }
}

// Implicit-GEMM conv, 32x32x16 MFMA. Block = 8 rows x 32 px x 64 oc; 4 waves =
// 2 row-groups (4 rows = M=128) x 2 oc-halves (N=32). B per wave per tap = 2KB
// (halves L1 traffic). LDS holds xn only, double-buffered; powers computed
// in-register at q==0 A-load. Staging for chunk cc+1 issued under cc's taps.
__global__ __launch_bounds__(256, 2) void conv_kernel(
        const unsigned short* __restrict__ xn2,
        const unsigned short* __restrict__ Wb3,
        float* __restrict__ out) {
    // L[buf][slot = (row*4 + g2)*34 + px][16B], g2 = ch-granule (8ch): 2x21760 B
    __shared__ __align__(16) unsigned char L[2][NSLOT * 16];

    int bid = blockIdx.x;
    int bx  = bid & 7;           // x tile (8)
    int by  = (bid >> 3) & 31;   // y tile (32)
    int b   = bid >> 8;          // batch (8)
    int x0  = bx * 32;
    int y0  = by * 8;
    int tid  = threadIdx.x;
    int lane = tid & 63;
    int w    = tid >> 6;
    int rg   = w >> 1;           // row-group: rows {4rg..4rg+3}
    int oh   = w & 1;            // oc half
    int l31  = lane & 31;
    int kb   = lane >> 5;        // k-granule bit

    f32x16 acc[4];
    #pragma unroll
    for (int mt = 0; mt < 4; ++mt)
        #pragma unroll
        for (int r = 0; r < 16; ++r)
            acc[mt][r] = 0.f;

    // ---- staging geometry (cc-invariant): slot = tid + it*256 ----
    int offg[6];
    bool vld[6], wrk[6];
    #pragma unroll
    for (int it = 0; it < 6; ++it) {
        int slot = tid + it * 256;
        bool ok  = slot < NSLOT;
        int ii   = ok ? slot : 0;
        int row  = ii / 136;             // 136 = 4*34
        int rem  = ii - row * 136;
        int g2   = rem / 34;
        int px   = rem - g2 * 34;
        int yy   = y0 - 1 + row;
        int xx   = x0 - 1 + px;
        bool inb = ok && (unsigned)yy < 256u && (unsigned)xx < 256u;
        offg[it] = (yy * 256 + xx) * 32 + g2 * 8;
        vld[it]  = inb;
        wrk[it]  = ok;
    }

    const unsigned short* xpb = xn2 + (size_t)b * HWW * 32;
    const bf16x8* wlane = (const bf16x8*)Wb3 + lane;

    // ---- prologue: bulk-stage chunk 0 into L[0] ----
    u32x4 rs[6];
    #pragma unroll
    for (int it = 0; it < 6; ++it) {
        u32x4 v = (u32x4){0u, 0u, 0u, 0u};
        if (vld[it]) v = *(const u32x4*)(xpb + offg[it]);
        rs[it] = v;
    }
    #pragma unroll
    for (int it = 0; it < 6; ++it)
        if (wrk[it]) *(u32x4*)(&L[0][(tid + it * 256) * 16]) = rs[it];

    #pragma unroll 1
    for (int cc = 0; cc < 4; ++cc) {
        __syncthreads();               // staged buf ready; prev readers done
        const unsigned char* pa = &L[cc & 1][0] + (kb * 34 + l31) * 16;
        const unsigned short* xpn = xpb + (size_t)(cc + 1) * PLANE;
        const bf16x8* wcc = wlane + (size_t)cc * 4 * 64;

        bf16x8 bv[2][2];               // [buf][kh], nt fixed = oh
        #pragma unroll
        for (int kh = 0; kh < 2; ++kh)
            bv[0][kh] = wcc[(kh * 2 + oh) * 64];

        // issue chunk cc+1 staging loads (behind tap-0 B in vmcnt queue;
        // they fly under the 27 taps and are consumed by the ds_write below)
        if (cc < 3) {
            #pragma unroll
            for (int it = 0; it < 6; ++it) {
                u32x4 v = (u32x4){0u, 0u, 0u, 0u};
                if (vld[it]) v = *(const u32x4*)(xpn + offg[it]);
                rs[it] = v;
            }
        }

        bf16x8 av1[4][2], avp[4][2];

        #pragma unroll
        for (int tq = 0; tq < 27; ++tq) {
            const int cur = tq & 1, nxt = cur ^ 1;
            const int q  = tq % 3;
            const int sp = tq / 3;
            const int ky = sp / 3, kx = sp % 3;

            if (tq < 26) {
                #pragma unroll
                for (int kh = 0; kh < 2; ++kh)
                    bv[nxt][kh] = wcc[((tq + 1) * 16 + kh * 2 + oh) * 64];
            }

            if (q == 0) {
                #pragma unroll
                for (int mt = 0; mt < 4; ++mt)
                    #pragma unroll
                    for (int kh = 0; kh < 2; ++kh)
                        av1[mt][kh] = *(const bf16x8*)(pa
                            + (((4 * rg + mt + ky) * 4 + kh * 2) * 34 + kx) * 16);
            } else if (q == 1) {
                #pragma unroll
                for (int mt = 0; mt < 4; ++mt)
                    #pragma unroll
                    for (int kh = 0; kh < 2; ++kh)
                        avp[mt][kh] = frag_sq(av1[mt][kh]);
            } else {
                #pragma unroll
                for (int mt = 0; mt < 4; ++mt)
                    #pragma unroll
                    for (int kh = 0; kh < 2; ++kh)
                        avp[mt][kh] = frag_cube(av1[mt][kh]);
            }

            __builtin_amdgcn_s_setprio(1);
            #pragma unroll
            for (int kh = 0; kh < 2; ++kh)
                #pragma unroll
                for (int mt = 0; mt < 4; ++mt)
                    acc[mt] = __builtin_amdgcn_mfma_f32_32x32x16_bf16(
                        (q == 0) ? av1[mt][kh] : avp[mt][kh],
                        bv[cur][kh], acc[mt], 0, 0, 0);
            __builtin_amdgcn_s_setprio(0);
        }

        // write staged chunk cc+1 into the back buffer
        if (cc < 3) {
            unsigned char* Pn = &L[(cc & 1) ^ 1][0];
            #pragma unroll
            for (int it = 0; it < 6; ++it)
                if (wrk[it]) *(u32x4*)(Pn + (tid + it * 256) * 16) = rs[it];
        }
    }

    // ---- epilogue: fused PixelUnshuffle(2) ----
    // C/D 32x32: col(oc) = lane&31, row(px) = (reg&3) + 8*(reg>>2) + 4*(lane>>5)
    int ocb = oh * 32 + l31;
    #pragma unroll
    for (int mt = 0; mt < 4; ++mt) {
        int y  = y0 + 4 * rg + mt;
        int s  = mt & 1;                 // y&1 (y0, 4rg even)
        int y2 = y >> 1;
        #pragma unroll
        for (int p = 0; p < 8; ++p) {
            const int r  = (p & 1) + (p >> 1) * 4;       // 0,1,4,5,8,9,12,13
            int px = (r & 3) + 8 * (r >> 2) + 4 * kb;
            int x  = x0 + px;
            int ch = ocb * 4 + s * 2 + (x & 1);
            int x2 = x >> 1;
            size_t off = ((size_t)(b * 256 + ch) * 128 + y2) * 128 + x2;
            f32x2 v;
            v.x = acc[mt][r];
            v.y = acc[mt][r + 2];
            *(f32x2*)(out + off) = v;
        }
    }
}

extern "C" void kernel_launch(void* const* d_in, const int* in_sizes, int n_in,
                              void* d_out, int out_size, void* d_ws, size_t ws_size,
                              hipStream_t stream) {
    const float* x     = (const float*)d_in[0];
    const float* gamma = (const float*)d_in[1];
    const float* beta  = (const float*)d_in[2];
    const float* Wc    = (const float*)d_in[3];
    float* out = (float*)d_out;

    const size_t xn_bytes = (size_t)4 * PLANE * 2;               // 134217728
    const size_t wb_bytes = (size_t)27648 * 16;                  // 442368
    if (ws_size < xn_bytes + wb_bytes) return;                   // visible failure
    unsigned short* xn2 = (unsigned short*)d_ws;
    unsigned short* Wb3 = (unsigned short*)((char*)d_ws + xn_bytes);

    hipLaunchKernelGGL(prep_w, dim3(108), dim3(256), 0, stream, Wc, Wb3);
    hipLaunchKernelGGL(ln_kernel, dim3(2048), dim3(256), 0, stream, x, gamma, beta, xn2);
    hipLaunchKernelGGL(conv_kernel, dim3(2048), dim3(256), 0, stream, xn2, Wb3, out);
}

// Round 8
// 321.536 us; speedup vs baseline: 54.5480x; 28.4472x over previous
//
#include <hip/hip_runtime.h>
#include <hip/hip_bf16.h>
#include <stdint.h>

#define BB   8
#define CCH  128
#define HH   256
#define WWD  256
#define OCC  64
#define HWW  (HH*WWD)
#define PLANE (BB*HWW*32)          // elems per 32-ch plane of xn2

typedef __attribute__((ext_vector_type(8)))  short  bf16x8;
typedef __attribute__((ext_vector_type(16))) float  f32x16;
typedef __attribute__((ext_vector_type(4)))  unsigned int u32x4;
typedef __attribute__((ext_vector_type(2)))  float  f32x2;

static __device__ __forceinline__ unsigned cvt_pk_bf16(float lo, float hi) {
    unsigned r;
    asm("v_cvt_pk_bf16_f32 %0, %1, %2" : "=v"(r) : "v"(lo), "v"(hi));
    return r;
}
static __device__ __forceinline__ float bf16lo_to_f(unsigned u) {
    union { unsigned u; float f; } c; c.u = u << 16; return c.f;
}
static __device__ __forceinline__ float bf16hi_to_f(unsigned u) {
    union { unsigned u; float f; } c; c.u = u & 0xffff0000u; return c.f;
}

// Repack Wc (OC, Q*C, 3, 3) fp32 -> Wb3 in 32x32x16-fragment lane order.
// frag f = ((tq*4 + cc)*4) + kh*2 + nt, tq = tap*3 + q.
// lane -> oc = nt*32 + (lane&31), k = cc*32 + kh*16 + (lane>>5)*8 + j (j=0..7).
__global__ void prep_w(const float* __restrict__ Wc, unsigned short* __restrict__ Wb3) {
    int t = blockIdx.x * 256 + threadIdx.x;       // 27648 tasks, one bf16x8 each
    int lane = t & 63;
    int f    = t >> 6;                            // 0..431
    int nt   = f & 1;
    int kh   = (f >> 1) & 1;
    int cc   = (f >> 2) & 3;
    int tq   = f >> 4;                            // 0..26
    int q    = tq % 3;
    int tap  = tq / 3;
    int oc   = nt * 32 + (lane & 31);
    int kb   = cc * 32 + kh * 16 + (lane >> 5) * 8;
    u32x4 o;
    #pragma unroll
    for (int k = 0; k < 4; ++k) {
        float v0 = Wc[(size_t)(oc * 384 + q * 128 + kb + 2 * k) * 9 + tap];
        float v1 = Wc[(size_t)(oc * 384 + q * 128 + kb + 2 * k + 1) * 9 + tap];
        o[k] = cvt_pk_bf16(v0, v1);
    }
    *(u32x4*)(Wb3 + (size_t)t * 8) = o;
}

// Per-pixel LayerNorm over C=128; write xn2 as 4 planes [cc][b][y][x][32ch] bf16
__global__ __launch_bounds__(256) void ln_kernel(
        const float* __restrict__ x, const float* __restrict__ gamma,
        const float* __restrict__ beta, unsigned short* __restrict__ xn2) {
    int p  = blockIdx.x * 256 + threadIdx.x;      // global pixel
    int b  = p >> 16;
    int hw = p & 65535;
    const float* xb = x + (size_t)b * CCH * HWW + hw;
    unsigned buf[64];
    float sum = 0.f, sumsq = 0.f;
    #pragma unroll
    for (int cp = 0; cp < 64; ++cp) {
        float v0 = xb[(size_t)(2 * cp) * HWW];
        float v1 = xb[(size_t)(2 * cp + 1) * HWW];
        sum   += v0 + v1;
        sumsq += v0 * v0 + v1 * v1;
        buf[cp] = cvt_pk_bf16(v0, v1);
    }
    float mu  = sum * (1.f / 128.f);
    float var = sumsq * (1.f / 128.f) - mu * mu;
    float rs  = rsqrtf(var + 1e-5f);
    size_t pix = (size_t)p * 32;
    #pragma unroll
    for (int g = 0; g < 16; ++g) {
        u32x4 o;
        #pragma unroll
        for (int k = 0; k < 4; ++k) {
            int cp = g * 4 + k;
            float f0 = bf16lo_to_f(buf[cp]);
            float f1 = bf16hi_to_f(buf[cp]);
            int c0 = cp * 2, c1 = cp * 2 + 1;
            float y0 = fmaf((f0 - mu) * rs, gamma[c0], beta[c0]);
            float y1 = fmaf((f1 - mu) * rs, gamma[c1], beta[c1]);
            o[k] = cvt_pk_bf16(y0, y1);
        }
        *(u32x4*)(xn2 + (size_t)(g >> 2) * PLANE + pix + (g & 3) * 8) = o;
    }
}

// Implicit-GEMM conv, 32x32x16 MFMA. Block = 8 rows x 32 px x 64 oc; 4 waves =
// 2 row-groups x 2 oc-halves; wave = 4 rows (M=128) x 32 oc (N=32) so each
// B-fragment feeds 4 MFMAs (B L2-stream demand 32 B/cyc/CU < 56 cap).
// Powers staged in LDS (v5-proven); T14 staging split; tap-level A/B dbuf.
__global__ __launch_bounds__(256, 2) void conv_kernel(
        const unsigned short* __restrict__ xn2,
        const unsigned short* __restrict__ Wb3,
        float* __restrict__ out) {
    // P[row 10][slot 12 = q*4 + g2][px 34][16B], g2 = kh*2 + kb : 65280 B
    __shared__ __align__(16) unsigned char P[10 * 12 * 34 * 16];

    int bid = blockIdx.x;
    int bx  = bid & 7;          // x tile
    int by  = (bid >> 3) & 31;  // y tile
    int b   = bid >> 8;
    int x0  = bx * 32;
    int y0  = by * 8;
    int tid  = threadIdx.x;
    int lane = tid & 63;
    int w    = tid >> 6;
    int rg   = w >> 1;          // row-group: rows {4rg..4rg+3}
    int oh   = w & 1;           // oc half
    int l31  = lane & 31;
    int kb   = lane >> 5;       // k-granule bit

    f32x16 acc[4];
    #pragma unroll
    for (int mt = 0; mt < 4; ++mt)
        #pragma unroll
        for (int r = 0; r < 16; ++r)
            acc[mt][r] = 0.f;

    // ---- staging geometry (cc-invariant): it = row*136 + px*4 + g2 ----
    int offg[6];                 // elem offset within a plane
    int woff[6];                 // LDS offset in 16B units (q=0 slot)
    bool vldf[6], wrf[6];
    #pragma unroll
    for (int it = 0; it < 6; ++it) {
        int item = tid + it * 256;
        bool ok  = item < 1360;
        int ii   = ok ? item : 0;
        int row  = ii / 136;
        int rem  = ii - row * 136;
        int px   = rem >> 2;
        int g2   = rem & 3;
        int yy   = y0 - 1 + row;
        int xx   = x0 - 1 + px;
        bool inb = ok && (unsigned)yy < 256u && (unsigned)xx < 256u;
        offg[it] = (yy * 256 + xx) * 32 + g2 * 8;
        woff[it] = (row * 12 + g2) * 34 + px;
        vldf[it] = inb;
        wrf[it]  = ok;
    }

    const unsigned short* xpb = xn2 + (size_t)b * HWW * 32;
    const bf16x8* wlane = (const bf16x8*)Wb3 + lane;
    const unsigned char* pa = P + ((size_t)kb * 34 + l31) * 16;  // lane part of A addr

    // ---- prologue: issue chunk-0 staging loads ----
    u32x4 rs[6];
    #pragma unroll
    for (int it = 0; it < 6; ++it) {
        u32x4 v = (u32x4){0u, 0u, 0u, 0u};
        if (vldf[it]) v = *(const u32x4*)(xpb + offg[it]);
        rs[it] = v;
    }

    #pragma unroll 1
    for (int cc = 0; cc < 4; ++cc) {
        if (cc > 0) __syncthreads();          // all waves done reading prev chunk
        // ---- write powers to LDS from staged regs ----
        #pragma unroll
        for (int it = 0; it < 6; ++it) {
            if (!wrf[it]) continue;
            u32x4 u1 = rs[it];
            u32x4 u2, u3;
            #pragma unroll
            for (int k = 0; k < 4; ++k) {
                float f0 = bf16lo_to_f(u1[k]);
                float f1 = bf16hi_to_f(u1[k]);
                float s0 = f0 * f0, s1 = f1 * f1;
                u2[k] = cvt_pk_bf16(s0, s1);
                u3[k] = cvt_pk_bf16(s0 * f0, s1 * f1);
            }
            unsigned char* cell = P + (size_t)woff[it] * 16;
            *(u32x4*)(cell)            = u1;   // q=0
            *(u32x4*)(cell + 4*34*16)  = u2;   // q=1
            *(u32x4*)(cell + 8*34*16)  = u3;   // q=2
        }
        __syncthreads();

        // ---- issue chunk cc+1 staging loads (fly under the MFMAs below) ----
        if (cc < 3) {
            const unsigned short* xpn = xpb + (size_t)(cc + 1) * PLANE;
            #pragma unroll
            for (int it = 0; it < 6; ++it) {
                u32x4 v = (u32x4){0u, 0u, 0u, 0u};
                if (vldf[it]) v = *(const u32x4*)(xpn + offg[it]);
                rs[it] = v;
            }
        }

        // ---- 27 taps, software-pipelined A/B fragment prefetch ----
        const bf16x8* wcc = wlane + (size_t)cc * 4 * 64;
        bf16x8 av[2][4][2], bv[2][2];         // [buf][mt][kh] / [buf][kh]
        #pragma unroll
        for (int mt = 0; mt < 4; ++mt)
            #pragma unroll
            for (int kh = 0; kh < 2; ++kh)
                av[0][mt][kh] = *(const bf16x8*)(pa
                    + (size_t)(((4 * rg + mt) * 12 + kh * 2) * 34) * 16);
        #pragma unroll
        for (int kh = 0; kh < 2; ++kh)
            bv[0][kh] = wcc[(kh * 2 + oh) * 64];

        #pragma unroll
        for (int tq = 0; tq < 27; ++tq) {
            const int cur = tq & 1, nxt = cur ^ 1;
            if (tq < 26) {
                const int t2 = tq + 1;
                const int ky = t2 / 9, kx = (t2 / 3) % 3, q = t2 % 3;
                #pragma unroll
                for (int mt = 0; mt < 4; ++mt)
                    #pragma unroll
                    for (int kh = 0; kh < 2; ++kh)
                        av[nxt][mt][kh] = *(const bf16x8*)(pa
                            + (size_t)((((4 * rg + mt + ky) * 12 + q * 4 + kh * 2) * 34)
                                       + kx) * 16);
                #pragma unroll
                for (int kh = 0; kh < 2; ++kh)
                    bv[nxt][kh] = wcc[((size_t)t2 * 16 + kh * 2 + oh) * 64];
            }
            __builtin_amdgcn_s_setprio(1);
            #pragma unroll
            for (int kh = 0; kh < 2; ++kh)
                #pragma unroll
                for (int mt = 0; mt < 4; ++mt)
                    acc[mt] = __builtin_amdgcn_mfma_f32_32x32x16_bf16(
                        av[cur][mt][kh], bv[cur][kh], acc[mt], 0, 0, 0);
            __builtin_amdgcn_s_setprio(0);
        }
    }

    // ---- epilogue: fused PixelUnshuffle(2) ----
    // C/D 32x32: col(oc) = lane&31, row(px) = (reg&3) + 8*(reg>>2) + 4*(lane>>5)
    int ocb = oh * 32 + l31;
    #pragma unroll
    for (int mt = 0; mt < 4; ++mt) {
        int y  = y0 + 4 * rg + mt;
        int s  = mt & 1;                 // y&1 (y0, 4rg even)
        int y2 = y >> 1;
        #pragma unroll
        for (int p = 0; p < 8; ++p) {
            const int r  = (p & 1) + (p >> 1) * 4;       // 0,1,4,5,8,9,12,13
            int px = (r & 3) + 8 * (r >> 2) + 4 * kb;
            int x  = x0 + px;
            int ch = ocb * 4 + s * 2 + (x & 1);
            int x2 = x >> 1;
            size_t off = ((size_t)(b * 256 + ch) * 128 + y2) * 128 + x2;
            f32x2 v;
            v.x = acc[mt][r];
            v.y = acc[mt][r + 2];
            *(f32x2*)(out + off) = v;
        }
    }
}

extern "C" void kernel_launch(void* const* d_in, const int* in_sizes, int n_in,
                              void* d_out, int out_size, void* d_ws, size_t ws_size,
                              hipStream_t stream) {
    const float* x     = (const float*)d_in[0];
    const float* gamma = (const float*)d_in[1];
    const float* beta  = (const float*)d_in[2];
    const float* Wc    = (const float*)d_in[3];
    float* out = (float*)d_out;

    const size_t xn_bytes = (size_t)4 * PLANE * 2;               // 134217728
    const size_t wb_bytes = (size_t)27648 * 16;                  // 442368
    if (ws_size < xn_bytes + wb_bytes) return;                   // visible failure
    unsigned short* xn2 = (unsigned short*)d_ws;
    unsigned short* Wb3 = (unsigned short*)((char*)d_ws + xn_bytes);

    hipLaunchKernelGGL(prep_w, dim3(108), dim3(256), 0, stream, Wc, Wb3);
    hipLaunchKernelGGL(ln_kernel, dim3(2048), dim3(256), 0, stream, x, gamma, beta, xn2);
    hipLaunchKernelGGL(conv_kernel, dim3(2048), dim3(256), 0, stream, xn2, Wb3, out);
}